// Round 5
// baseline (6132.640 us; speedup 1.0000x reference)
//
#include <hip/hip_runtime.h>
#include <math.h>

#define THR  0.05f
#define BETA 0.9181805491303656f
#define B_SZ 64
#define T_STEPS 25

__device__ __forceinline__ float sigf(float x) { return 1.0f / (1.0f + __expf(-x)); }
__device__ __forceinline__ float tanh_fast(float x) {
    const float xc = fminf(fmaxf(x, -10.0f), 10.0f);
    const float e = __expf(2.0f * xc);
    return (e - 1.0f) / (e + 1.0f);
}

// ---------------------------------------------------------------------------
// Repack conv weights from (4*Ch, CIN, 3, 3) [OIHW] to [c][ci][tap][gate]
// so each (c, ci)'s 36 gate-tap weights are CONSECUTIVE -> scalar s_load path.
// ---------------------------------------------------------------------------
__global__ __launch_bounds__(256) void repack_kernel(
    const float* __restrict__ wt, float* __restrict__ wr, int Ch, int CIN)
{
    const int n = 4 * Ch * CIN * 9;
    for (int i = blockIdx.x * 256 + threadIdx.x; i < n; i += gridDim.x * 256) {
        const int g   = i & 3;
        const int tap = (i >> 2) % 9;
        const int ci  = (i / 36) % CIN;
        const int c   = i / (36 * CIN);
        wr[i] = wt[(((size_t)(g * Ch + c)) * CIN + ci) * 9 + tap];
    }
}

// ---------------------------------------------------------------------------
// Fused ConvLSTM step, wave-per-channel / lanes-per-pixel layout.
// Wave handles CITERS uniform channels -> weights via SGPR s_load (zero VMEM
// in the inner loop). Lanes cover R rows x W/2 pixel-pairs. Input tile staged
// in LDS in ci-chunks; pooled staging reads via float4 (4x fewer VMEM).
// cil loop unroll capped at 2 to stay I$-resident.
// ---------------------------------------------------------------------------
template<int Cin, int Ch, int H, int W, int R, int CSPLIT, int CHUNK, bool POOL_IN, int MINW>
__global__ __launch_bounds__(256, MINW) void conv_lstm(
    const float* __restrict__ xin,    // raw (B,Cin,H,W) or prev mem (B,Cin,2H,2W)
    const float* __restrict__ memin,  // (B,Ch,H,W)
    const float* __restrict__ synin,
    float* __restrict__ synout,
    float* __restrict__ memout,
    const float* __restrict__ wr,     // repacked [c][ci][tap][gate]
    const float* __restrict__ bias)   // (4*Ch)
{
    constexpr int CIN = Cin + Ch;
    constexpr int R2 = R + 2;
    constexpr int SW = W + 4;
    constexpr int ROWLANES = W / 2;
    constexpr int NROUNDS = CIN / CHUNK;
    constexpr int CITERS = Ch / (CSPLIT * 4);
    static_assert(R * ROWLANES == 64, "wave must cover R x W/2 pixel pairs");
    static_assert(CIN % CHUNK == 0, "");
    static_assert(CITERS >= 1, "");

    __shared__ float tile[CHUNK * R2 * SW];

    const int tid = threadIdx.x;
    const int bid = blockIdx.x;
    const int cs = bid % CSPLIT;
    const int rs = (bid / CSPLIT) % (H / R);
    const int b  = bid / (CSPLIT * (H / R));
    const int r0 = rs * R;
    const int c0 = cs * (Ch / CSPLIT);

    const int lane = tid & 63;
    const int wid  = tid >> 6;
    const int ly   = lane / ROWLANES;         // local row 0..R-1
    const int lx   = 2 * (lane % ROWLANES);   // x0 (even)
    const int gy_out = r0 + ly;

    // wave-uniform channel ids (forces SGPR/scalar-load path for weights)
    int cu[CITERS];
    #pragma unroll
    for (int k = 0; k < CITERS; ++k)
        cu[k] = __builtin_amdgcn_readfirstlane(c0 + k * 4 + wid);

    // accumulators: acc[k][gate*2 + p], gates i,f,g,o
    float acc[CITERS][8];
    #pragma unroll
    for (int k = 0; k < CITERS; ++k) {
        const float bi = bias[cu[k]];
        const float bf = bias[cu[k] + Ch];
        const float bg = bias[cu[k] + 2 * Ch];
        const float bo = bias[cu[k] + 3 * Ch];
        acc[k][0] = bi; acc[k][1] = bi;
        acc[k][2] = bf; acc[k][3] = bf;
        acc[k][4] = bg; acc[k][5] = bg;
        acc[k][6] = bo; acc[k][7] = bo;
    }

    for (int rd = 0; rd < NROUNDS; ++rd) {
        const int k0 = rd * CHUNK;
        if (rd) __syncthreads();

        // zero the 4 pad columns (col 0 and cols W+1..W+3)
        for (int i = tid; i < CHUNK * R2 * 4; i += 256) {
            const int col = i & 3;
            const int row = i >> 2;
            tile[row * SW + (col == 0 ? 0 : W + col)] = 0.0f;
        }
        // interior: one pixel-pair per iteration, vectorized loads
        for (int i = tid; i < CHUNK * R2 * ROWLANES; i += 256) {
            const int px  = i % ROWLANES;
            const int ry  = (i / ROWLANES) % R2;
            const int cil = i / (ROWLANES * R2);
            const int ci  = k0 + cil;
            const int gy  = r0 + ry - 1;
            float vx = 0.0f, vy = 0.0f;
            if (gy >= 0 && gy < H) {
                if (POOL_IN && ci < Cin) {
                    const float* mp = xin + (((size_t)b * Cin + ci) * (2 * H) + 2 * gy) * (2 * W) + 4 * px;
                    const float4 q0 = *(const float4*)mp;
                    const float4 q1 = *(const float4*)(mp + 2 * W);
                    vx = ((fmaxf(fmaxf(q0.x, q0.y), fmaxf(q1.x, q1.y)) - THR) > 0.0f) ? 1.0f : 0.0f;
                    vy = ((fmaxf(fmaxf(q0.z, q0.w), fmaxf(q1.z, q1.w)) - THR) > 0.0f) ? 1.0f : 0.0f;
                } else if (ci < Cin) {
                    const float2 q = *(const float2*)(xin + (((size_t)b * Cin + ci) * H + gy) * W + 2 * px);
                    vx = q.x; vy = q.y;
                } else {
                    const float2 q = *(const float2*)(memin + (((size_t)b * Ch + (ci - Cin)) * H + gy) * W + 2 * px);
                    vx = q.x; vy = q.y;
                }
            }
            const int t0 = (cil * R2 + ry) * SW + 1 + 2 * px;
            tile[t0]     = vx;
            tile[t0 + 1] = vy;
        }
        __syncthreads();

        #pragma unroll 2
        for (int cil = 0; cil < CHUNK; ++cil) {
            // 4-wide strips for the pixel pair, 3 rows: 6x ds_read_b64
            float s[3][4];
            #pragma unroll
            for (int dy = 0; dy < 3; ++dy) {
                const float* rp = &tile[(cil * R2 + ly + dy) * SW + lx];
                const float2 a  = *(const float2*)rp;
                const float2 bq = *(const float2*)(rp + 2);
                s[dy][0] = a.x; s[dy][1] = a.y; s[dy][2] = bq.x; s[dy][3] = bq.y;
            }
            #pragma unroll
            for (int k = 0; k < CITERS; ++k) {
                // uniform address -> s_load of 36 consecutive floats
                const float* wp = wr + ((size_t)cu[k] * CIN + (k0 + cil)) * 36;
                #pragma unroll
                for (int tap = 0; tap < 9; ++tap) {
                    const int dy = tap / 3, dx = tap % 3;
                    const float wi  = wp[tap * 4 + 0];
                    const float wf  = wp[tap * 4 + 1];
                    const float wg_ = wp[tap * 4 + 2];
                    const float wo  = wp[tap * 4 + 3];
                    #pragma unroll
                    for (int p = 0; p < 2; ++p) {
                        const float v = s[dy][p + dx];
                        acc[k][0 + p] = fmaf(v, wi,  acc[k][0 + p]);
                        acc[k][2 + p] = fmaf(v, wf,  acc[k][2 + p]);
                        acc[k][4 + p] = fmaf(v, wg_, acc[k][4 + p]);
                        acc[k][6 + p] = fmaf(v, wo,  acc[k][6 + p]);
                    }
                }
            }
        }
    }

    // epilogue: LSTM state update, pixel-pair vectorized
    #pragma unroll
    for (int k = 0; k < CITERS; ++k) {
        const int c = c0 + k * 4 + wid;
        const size_t base = (((size_t)b * Ch + c) * H + gy_out) * W + lx;
        const float2 synv = *(const float2*)(synin + base);
        float sv[2] = {synv.x, synv.y};
        float so[2], mo[2];
        #pragma unroll
        for (int p = 0; p < 2; ++p) {
            const float syn = sigf(acc[k][2 + p]) * sv[p] + sigf(acc[k][0 + p]) * tanh_fast(acc[k][4 + p]);
            so[p] = syn;
            mo[p] = sigf(acc[k][6 + p]) * tanh_fast(syn);
        }
        *(float2*)(synout + base) = make_float2(so[0], so[1]);
        *(float2*)(memout + base) = make_float2(mo[0], mo[1]);
    }
}

// ---------------------------------------------------------------------------
// Fused maxpool(m3) -> spk3 -> cur4 = spk3 @ fc1_w.T + b -> Leaky(mem4).
// ---------------------------------------------------------------------------
__global__ __launch_bounds__(256) void fc1_pool_kernel(
    const float* __restrict__ m3,    // (B, 64, 4, 32)
    const float* __restrict__ wt,    // (512, 2048)
    const float* __restrict__ bias,
    float* __restrict__ mem4,
    float* __restrict__ spk4)
{
    const int wid = (blockIdx.x * 256 + threadIdx.x) >> 6;
    const int lane = threadIdx.x & 63;
    const int og = wid & 63;
    const int b = wid >> 6;
    const int o0 = og * 8;

    float acc[8] = {0, 0, 0, 0, 0, 0, 0, 0};
    for (int it = 0; it < 8; ++it) {
        const int k = (it * 64 + lane) * 4;
        const int c = k >> 5;
        const int rem = k & 31;
        const int ph = rem >> 4;
        const int pw = rem & 15;
        const float* mp = m3 + (((size_t)b * 64 + c) * 4 + 2 * ph) * 32 + 2 * pw;
        const float4 r0 = *(const float4*)mp;
        const float4 r1 = *(const float4*)(mp + 4);
        const float4 q0 = *(const float4*)(mp + 32);
        const float4 q1 = *(const float4*)(mp + 36);
        float4 sv;
        sv.x = ((fmaxf(fmaxf(r0.x, r0.y), fmaxf(q0.x, q0.y)) - THR) > 0.0f) ? 1.0f : 0.0f;
        sv.y = ((fmaxf(fmaxf(r0.z, r0.w), fmaxf(q0.z, q0.w)) - THR) > 0.0f) ? 1.0f : 0.0f;
        sv.z = ((fmaxf(fmaxf(r1.x, r1.y), fmaxf(q1.x, q1.y)) - THR) > 0.0f) ? 1.0f : 0.0f;
        sv.w = ((fmaxf(fmaxf(r1.z, r1.w), fmaxf(q1.z, q1.w)) - THR) > 0.0f) ? 1.0f : 0.0f;
        #pragma unroll
        for (int j = 0; j < 8; ++j) {
            const float4 wv = *(const float4*)(wt + (size_t)(o0 + j) * 2048 + k);
            acc[j] = fmaf(sv.x, wv.x, acc[j]);
            acc[j] = fmaf(sv.y, wv.y, acc[j]);
            acc[j] = fmaf(sv.z, wv.z, acc[j]);
            acc[j] = fmaf(sv.w, wv.w, acc[j]);
        }
    }
    float mine = 0.0f;
    #pragma unroll
    for (int j = 0; j < 8; ++j) {
        float a = acc[j];
        #pragma unroll
        for (int off = 32; off; off >>= 1) a += __shfl_xor(a, off, 64);
        if (lane == j) mine = a;
    }
    if (lane < 8) {
        const int o = o0 + lane;
        const float cur = mine + bias[o];
        const int i4 = b * 512 + o;
        float m = mem4[i4];
        const float reset = (m > THR) ? 1.0f : 0.0f;
        m = BETA * m + cur - reset * THR;
        spk4[i4] = ((m - THR) > 0.0f) ? 1.0f : 0.0f;
        mem4[i4] = m;
    }
}

// ---------------------------------------------------------------------------
// cur5 = spk4 @ fc2_w.T + fc2_b; Leaky(mem5); writes spk_rec[t], mem_rec[t].
// ---------------------------------------------------------------------------
__global__ __launch_bounds__(256) void fc2_kernel(
    const float* __restrict__ spk4,
    const float* __restrict__ wt,
    const float* __restrict__ bias,
    float* __restrict__ mem5,
    float* __restrict__ out_spk,
    float* __restrict__ out_mem)
{
    const int wid = (blockIdx.x * 256 + threadIdx.x) >> 6;
    const int lane = threadIdx.x & 63;
    if (wid >= 2 * B_SZ) return;
    const int o = wid & 1;
    const int b = wid >> 1;
    const float* wr = wt + (size_t)o * 512;
    const float* sr = spk4 + (size_t)b * 512;
    float acc = 0.0f;
    #pragma unroll
    for (int i = 0; i < 8; ++i)
        acc = fmaf(sr[lane + i * 64], wr[lane + i * 64], acc);
    #pragma unroll
    for (int off = 32; off; off >>= 1) acc += __shfl_down(acc, off, 64);
    if (lane == 0) {
        const float cur = acc + bias[o];
        const int i5 = b * 2 + o;
        float m = mem5[i5];
        const float reset = (m > THR) ? 1.0f : 0.0f;
        m = BETA * m + cur - reset * THR;
        out_spk[i5] = ((m - THR) > 0.0f) ? 1.0f : 0.0f;
        out_mem[i5] = m;
        mem5[i5] = m;
    }
}

extern "C" void kernel_launch(void* const* d_in, const int* in_sizes, int n_in,
                              void* d_out, int out_size, void* d_ws, size_t ws_size,
                              hipStream_t stream) {
    (void)in_sizes; (void)n_in; (void)out_size; (void)ws_size;

    const float* x    = (const float*)d_in[0];
    const float* w1   = (const float*)d_in[1];
    const float* b1   = (const float*)d_in[2];
    const float* w2   = (const float*)d_in[3];
    const float* b2   = (const float*)d_in[4];
    const float* w3   = (const float*)d_in[5];
    const float* b3   = (const float*)d_in[6];
    const float* fc1w = (const float*)d_in[7];
    const float* fc1b = (const float*)d_in[8];
    const float* fc2w = (const float*)d_in[9];
    const float* fc2b = (const float*)d_in[10];

    float* out = (float*)d_out;
    float* ws = (float*)d_ws;

    const size_t N1 = (size_t)B_SZ * 16 * 16 * 128;
    const size_t N2 = (size_t)B_SZ * 32 * 8 * 64;
    const size_t N3 = (size_t)B_SZ * 64 * 4 * 32;

    size_t off = 0;
    float* syn1  = ws + off; off += N1;
    float* mem1a = ws + off; off += N1;
    float* mem1b = ws + off; off += N1;
    float* syn2  = ws + off; off += N2;
    float* mem2a = ws + off; off += N2;
    float* mem2b = ws + off; off += N2;
    float* syn3  = ws + off; off += N3;
    float* mem3a = ws + off; off += N3;
    float* mem3b = ws + off; off += N3;
    float* mem4  = ws + off; off += (size_t)B_SZ * 512;
    float* mem5  = ws + off; off += (size_t)B_SZ * 2;
    const size_t zero_elems = off;
    float* spk4 = ws + off; off += (size_t)B_SZ * 512;
    float* wr1  = ws + off; off += (size_t)4 * 16 * 17 * 9;
    float* wr2  = ws + off; off += (size_t)4 * 32 * 48 * 9;
    float* wr3  = ws + off; off += (size_t)4 * 64 * 96 * 9;

    hipMemsetAsync(d_ws, 0, zero_elems * sizeof(float), stream);

    repack_kernel<<<64, 256, 0, stream>>>(w1, wr1, 16, 17);
    repack_kernel<<<64, 256, 0, stream>>>(w2, wr2, 32, 48);
    repack_kernel<<<64, 256, 0, stream>>>(w3, wr3, 64, 96);

    float* m1r = mem1a; float* m1w = mem1b;
    float* m2r = mem2a; float* m2w = mem2b;
    float* m3r = mem3a; float* m3w = mem3b;

    for (int t = 0; t < T_STEPS; ++t) {
        const float* xt = x + (size_t)t * B_SZ * 16 * 128;

        // L1: R=1, CSPLIT=1, CHUNK=17 (1 round), CITERS=4.
        //     grid 64*16 = 1024, LDS 26.9KB -> 4 blocks/CU
        conv_lstm<1, 16, 16, 128, 1, 1, 17, false, 4><<<1024, 256, 0, stream>>>(
            xt, m1r, syn1, syn1, m1w, wr1, b1);
        // L2: R=2, CSPLIT=2, CHUNK=48 (1 round, no mid barriers), CITERS=4.
        //     grid 64*4*2 = 512, LDS 52.2KB -> 2 blocks/CU
        conv_lstm<16, 32, 8, 64, 2, 2, 48, true, 2><<<512, 256, 0, stream>>>(
            m1w, m2r, syn2, syn2, m2w, wr2, b2);
        // L3: R=4, CSPLIT=8, CHUNK=48 (2 rounds), CITERS=2.
        //     grid 64*8 = 512, LDS 41.5KB -> 2 blocks/CU
        conv_lstm<32, 64, 4, 32, 4, 8, 48, true, 2><<<512, 256, 0, stream>>>(
            m2w, m3r, syn3, syn3, m3w, wr3, b3);

        fc1_pool_kernel<<<1024, 256, 0, stream>>>(m3w, fc1w, fc1b, mem4, spk4);
        fc2_kernel<<<32, 256, 0, stream>>>(
            spk4, fc2w, fc2b, mem5, out + (size_t)t * 2 * B_SZ,
            out + 3200 + (size_t)t * 2 * B_SZ);

        float* tmp;
        tmp = m1r; m1r = m1w; m1w = tmp;
        tmp = m2r; m2r = m2w; m2w = tmp;
        tmp = m3r; m3r = m3w; m3w = tmp;
    }
}

// Round 6
// 4446.341 us; speedup vs baseline: 1.3793x; 1.3793x over previous
//
#include <hip/hip_runtime.h>
#include <math.h>

#define THR  0.05f
#define BETA 0.9181805491303656f
#define B_SZ 64
#define T_STEPS 25

__device__ __forceinline__ float sigf(float x) { return 1.0f / (1.0f + __expf(-x)); }
__device__ __forceinline__ float tanh_fast(float x) {
    const float xc = fminf(fmaxf(x, -10.0f), 10.0f);
    const float e = __expf(2.0f * xc);
    return (e - 1.0f) / (e + 1.0f);
}

// ---------------------------------------------------------------------------
// Repack conv weights from (4*Ch, CIN, 3, 3) [OIHW] to [c][ci][tap][gate]
// so each (c, ci)'s 36 gate-tap weights are CONSECUTIVE -> scalar s_load path.
// ---------------------------------------------------------------------------
__global__ __launch_bounds__(256) void repack_kernel(
    const float* __restrict__ wt, float* __restrict__ wr, int Ch, int CIN)
{
    const int n = 4 * Ch * CIN * 9;
    for (int i = blockIdx.x * 256 + threadIdx.x; i < n; i += gridDim.x * 256) {
        const int g   = i & 3;
        const int tap = (i >> 2) % 9;
        const int ci  = (i / 36) % CIN;
        const int c   = i / (36 * CIN);
        wr[i] = wt[(((size_t)(g * Ch + c)) * CIN + ci) * 9 + tap];
    }
}

// ---------------------------------------------------------------------------
// Fused ConvLSTM step, wave-per-channel / lanes-per-pixel layout.
// Wave handles CITERS uniform channels -> weights via SGPR s_load (zero VMEM
// in inner loop). Lanes cover R rows x W/P pixel-P-groups. Input staged in
// LDS ci-chunks. Outer cil loop blocked by UF (inner fully unrolled, outer
// pinned to unroll 1) to widen the load-hoisting window without I$ bloat.
// ---------------------------------------------------------------------------
template<int Cin, int Ch, int H, int W, int R, int CSPLIT, int CHUNK,
         bool POOL_IN, int MINW, int P, int UF>
__global__ __launch_bounds__(256, MINW) void conv_lstm(
    const float* __restrict__ xin,    // raw (B,Cin,H,W) or prev mem (B,Cin,2H,2W)
    const float* __restrict__ memin,  // (B,Ch,H,W)
    const float* __restrict__ synin,
    float* __restrict__ synout,
    float* __restrict__ memout,
    const float* __restrict__ wr,     // repacked [c][ci][tap][gate]
    const float* __restrict__ bias)   // (4*Ch)
{
    constexpr int CIN = Cin + Ch;
    constexpr int R2 = R + 2;
    constexpr int SW = W + 4;
    constexpr int ROWLANES = W / P;    // compute lanes per row
    constexpr int SPAIRS = W / 2;      // staging pixel-pairs per row
    constexpr int NROUNDS = CIN / CHUNK;
    constexpr int CITERS = Ch / (CSPLIT * 4);
    static_assert(R * ROWLANES == 64, "wave must cover R x W/P pixel groups");
    static_assert(CIN % CHUNK == 0, "");
    static_assert(CHUNK % UF == 0, "");
    static_assert(CITERS >= 1, "");

    __shared__ float tile[CHUNK * R2 * SW];

    const int tid = threadIdx.x;
    const int bid = blockIdx.x;
    const int cs = bid % CSPLIT;
    const int rs = (bid / CSPLIT) % (H / R);
    const int b  = bid / (CSPLIT * (H / R));
    const int r0 = rs * R;
    const int c0 = cs * (Ch / CSPLIT);

    const int lane = tid & 63;
    const int wid  = tid >> 6;
    const int ly   = lane / ROWLANES;         // local row 0..R-1
    const int lx   = P * (lane % ROWLANES);   // x0 (multiple of P)
    const int gy_out = r0 + ly;

    // wave-uniform channel ids (forces SGPR/scalar-load path for weights)
    int cu[CITERS];
    #pragma unroll
    for (int k = 0; k < CITERS; ++k)
        cu[k] = __builtin_amdgcn_readfirstlane(c0 + k * 4 + wid);

    // accumulators: acc[k][gate*P + p], gates i,f,g,o
    float acc[CITERS][4 * P];
    #pragma unroll
    for (int k = 0; k < CITERS; ++k) {
        const float bi = bias[cu[k]];
        const float bf = bias[cu[k] + Ch];
        const float bg = bias[cu[k] + 2 * Ch];
        const float bo = bias[cu[k] + 3 * Ch];
        #pragma unroll
        for (int p = 0; p < P; ++p) {
            acc[k][0 * P + p] = bi;
            acc[k][1 * P + p] = bf;
            acc[k][2 * P + p] = bg;
            acc[k][3 * P + p] = bo;
        }
    }

    for (int rd = 0; rd < NROUNDS; ++rd) {
        const int k0 = rd * CHUNK;
        if (rd) __syncthreads();

        // zero the 4 pad columns (col 0 and cols W+1..W+3)
        for (int i = tid; i < CHUNK * R2 * 4; i += 256) {
            const int col = i & 3;
            const int row = i >> 2;
            tile[row * SW + (col == 0 ? 0 : W + col)] = 0.0f;
        }
        // interior: one pixel-pair per iteration, vectorized loads
        for (int i = tid; i < CHUNK * R2 * SPAIRS; i += 256) {
            const int px  = i % SPAIRS;
            const int ry  = (i / SPAIRS) % R2;
            const int cil = i / (SPAIRS * R2);
            const int ci  = k0 + cil;
            const int gy  = r0 + ry - 1;
            float vx = 0.0f, vy = 0.0f;
            if (gy >= 0 && gy < H) {
                if (POOL_IN && ci < Cin) {
                    const float* mp = xin + (((size_t)b * Cin + ci) * (2 * H) + 2 * gy) * (2 * W) + 4 * px;
                    const float4 q0 = *(const float4*)mp;
                    const float4 q1 = *(const float4*)(mp + 2 * W);
                    vx = ((fmaxf(fmaxf(q0.x, q0.y), fmaxf(q1.x, q1.y)) - THR) > 0.0f) ? 1.0f : 0.0f;
                    vy = ((fmaxf(fmaxf(q0.z, q0.w), fmaxf(q1.z, q1.w)) - THR) > 0.0f) ? 1.0f : 0.0f;
                } else if (ci < Cin) {
                    const float2 q = *(const float2*)(xin + (((size_t)b * Cin + ci) * H + gy) * W + 2 * px);
                    vx = q.x; vy = q.y;
                } else {
                    const float2 q = *(const float2*)(memin + (((size_t)b * Ch + (ci - Cin)) * H + gy) * W + 2 * px);
                    vx = q.x; vy = q.y;
                }
            }
            const int t0 = (cil * R2 + ry) * SW + 1 + 2 * px;
            tile[t0]     = vx;
            tile[t0 + 1] = vy;
        }
        __syncthreads();

        #pragma unroll 1
        for (int cil0 = 0; cil0 < CHUNK; cil0 += UF) {
            #pragma unroll
            for (int u = 0; u < UF; ++u) {
                const int cil = cil0 + u;
                // strip for the pixel group, 3 rows of P+2 floats
                float s[3][P + 2];
                #pragma unroll
                for (int dy = 0; dy < 3; ++dy) {
                    const float* rp = &tile[(cil * R2 + ly + dy) * SW + lx];
                    if constexpr (P == 4) {
                        const float4 a  = *(const float4*)rp;
                        const float2 e  = *(const float2*)(rp + 4);
                        s[dy][0] = a.x; s[dy][1] = a.y; s[dy][2] = a.z; s[dy][3] = a.w;
                        s[dy][4] = e.x; s[dy][5] = e.y;
                    } else {
                        const float2 a  = *(const float2*)rp;
                        const float2 e  = *(const float2*)(rp + 2);
                        s[dy][0] = a.x; s[dy][1] = a.y; s[dy][2] = e.x; s[dy][3] = e.y;
                    }
                }
                #pragma unroll
                for (int k = 0; k < CITERS; ++k) {
                    // uniform address -> s_load of 36 consecutive floats
                    const float* wp = wr + ((size_t)cu[k] * CIN + (k0 + cil)) * 36;
                    #pragma unroll
                    for (int tap = 0; tap < 9; ++tap) {
                        const int dy = tap / 3, dx = tap % 3;
                        const float wi  = wp[tap * 4 + 0];
                        const float wf  = wp[tap * 4 + 1];
                        const float wg_ = wp[tap * 4 + 2];
                        const float wo  = wp[tap * 4 + 3];
                        #pragma unroll
                        for (int p = 0; p < P; ++p) {
                            const float v = s[dy][p + dx];
                            acc[k][0 * P + p] = fmaf(v, wi,  acc[k][0 * P + p]);
                            acc[k][1 * P + p] = fmaf(v, wf,  acc[k][1 * P + p]);
                            acc[k][2 * P + p] = fmaf(v, wg_, acc[k][2 * P + p]);
                            acc[k][3 * P + p] = fmaf(v, wo,  acc[k][3 * P + p]);
                        }
                    }
                }
            }
        }
    }

    // epilogue: LSTM state update, vectorized by P
    #pragma unroll
    for (int k = 0; k < CITERS; ++k) {
        const int c = c0 + k * 4 + wid;
        const size_t base = (((size_t)b * Ch + c) * H + gy_out) * W + lx;
        float sv[P], so[P], mo[P];
        if constexpr (P == 4) {
            const float4 q = *(const float4*)(synin + base);
            sv[0] = q.x; sv[1] = q.y; sv[2] = q.z; sv[3] = q.w;
        } else {
            const float2 q = *(const float2*)(synin + base);
            sv[0] = q.x; sv[1] = q.y;
        }
        #pragma unroll
        for (int p = 0; p < P; ++p) {
            const float syn = sigf(acc[k][1 * P + p]) * sv[p]
                            + sigf(acc[k][0 * P + p]) * tanh_fast(acc[k][2 * P + p]);
            so[p] = syn;
            mo[p] = sigf(acc[k][3 * P + p]) * tanh_fast(syn);
        }
        if constexpr (P == 4) {
            *(float4*)(synout + base) = make_float4(so[0], so[1], so[2], so[3]);
            *(float4*)(memout + base) = make_float4(mo[0], mo[1], mo[2], mo[3]);
        } else {
            *(float2*)(synout + base) = make_float2(so[0], so[1]);
            *(float2*)(memout + base) = make_float2(mo[0], mo[1]);
        }
    }
}

// ---------------------------------------------------------------------------
// Fused maxpool(m3) -> spk3 -> cur4 = spk3 @ fc1_w.T + b -> Leaky(mem4).
// ---------------------------------------------------------------------------
__global__ __launch_bounds__(256) void fc1_pool_kernel(
    const float* __restrict__ m3,    // (B, 64, 4, 32)
    const float* __restrict__ wt,    // (512, 2048)
    const float* __restrict__ bias,
    float* __restrict__ mem4,
    float* __restrict__ spk4)
{
    const int wid = (blockIdx.x * 256 + threadIdx.x) >> 6;
    const int lane = threadIdx.x & 63;
    const int og = wid & 63;
    const int b = wid >> 6;
    const int o0 = og * 8;

    float acc[8] = {0, 0, 0, 0, 0, 0, 0, 0};
    for (int it = 0; it < 8; ++it) {
        const int k = (it * 64 + lane) * 4;
        const int c = k >> 5;
        const int rem = k & 31;
        const int ph = rem >> 4;
        const int pw = rem & 15;
        const float* mp = m3 + (((size_t)b * 64 + c) * 4 + 2 * ph) * 32 + 2 * pw;
        const float4 r0 = *(const float4*)mp;
        const float4 r1 = *(const float4*)(mp + 4);
        const float4 q0 = *(const float4*)(mp + 32);
        const float4 q1 = *(const float4*)(mp + 36);
        float4 sv;
        sv.x = ((fmaxf(fmaxf(r0.x, r0.y), fmaxf(q0.x, q0.y)) - THR) > 0.0f) ? 1.0f : 0.0f;
        sv.y = ((fmaxf(fmaxf(r0.z, r0.w), fmaxf(q0.z, q0.w)) - THR) > 0.0f) ? 1.0f : 0.0f;
        sv.z = ((fmaxf(fmaxf(r1.x, r1.y), fmaxf(q1.x, q1.y)) - THR) > 0.0f) ? 1.0f : 0.0f;
        sv.w = ((fmaxf(fmaxf(r1.z, r1.w), fmaxf(q1.z, q1.w)) - THR) > 0.0f) ? 1.0f : 0.0f;
        #pragma unroll
        for (int j = 0; j < 8; ++j) {
            const float4 wv = *(const float4*)(wt + (size_t)(o0 + j) * 2048 + k);
            acc[j] = fmaf(sv.x, wv.x, acc[j]);
            acc[j] = fmaf(sv.y, wv.y, acc[j]);
            acc[j] = fmaf(sv.z, wv.z, acc[j]);
            acc[j] = fmaf(sv.w, wv.w, acc[j]);
        }
    }
    float mine = 0.0f;
    #pragma unroll
    for (int j = 0; j < 8; ++j) {
        float a = acc[j];
        #pragma unroll
        for (int off = 32; off; off >>= 1) a += __shfl_xor(a, off, 64);
        if (lane == j) mine = a;
    }
    if (lane < 8) {
        const int o = o0 + lane;
        const float cur = mine + bias[o];
        const int i4 = b * 512 + o;
        float m = mem4[i4];
        const float reset = (m > THR) ? 1.0f : 0.0f;
        m = BETA * m + cur - reset * THR;
        spk4[i4] = ((m - THR) > 0.0f) ? 1.0f : 0.0f;
        mem4[i4] = m;
    }
}

// ---------------------------------------------------------------------------
// cur5 = spk4 @ fc2_w.T + fc2_b; Leaky(mem5); writes spk_rec[t], mem_rec[t].
// ---------------------------------------------------------------------------
__global__ __launch_bounds__(256) void fc2_kernel(
    const float* __restrict__ spk4,
    const float* __restrict__ wt,
    const float* __restrict__ bias,
    float* __restrict__ mem5,
    float* __restrict__ out_spk,
    float* __restrict__ out_mem)
{
    const int wid = (blockIdx.x * 256 + threadIdx.x) >> 6;
    const int lane = threadIdx.x & 63;
    if (wid >= 2 * B_SZ) return;
    const int o = wid & 1;
    const int b = wid >> 1;
    const float* wr = wt + (size_t)o * 512;
    const float* sr = spk4 + (size_t)b * 512;
    float acc = 0.0f;
    #pragma unroll
    for (int i = 0; i < 8; ++i)
        acc = fmaf(sr[lane + i * 64], wr[lane + i * 64], acc);
    #pragma unroll
    for (int off = 32; off; off >>= 1) acc += __shfl_down(acc, off, 64);
    if (lane == 0) {
        const float cur = acc + bias[o];
        const int i5 = b * 2 + o;
        float m = mem5[i5];
        const float reset = (m > THR) ? 1.0f : 0.0f;
        m = BETA * m + cur - reset * THR;
        out_spk[i5] = ((m - THR) > 0.0f) ? 1.0f : 0.0f;
        out_mem[i5] = m;
        mem5[i5] = m;
    }
}

extern "C" void kernel_launch(void* const* d_in, const int* in_sizes, int n_in,
                              void* d_out, int out_size, void* d_ws, size_t ws_size,
                              hipStream_t stream) {
    (void)in_sizes; (void)n_in; (void)out_size; (void)ws_size;

    const float* x    = (const float*)d_in[0];
    const float* w1   = (const float*)d_in[1];
    const float* b1   = (const float*)d_in[2];
    const float* w2   = (const float*)d_in[3];
    const float* b2   = (const float*)d_in[4];
    const float* w3   = (const float*)d_in[5];
    const float* b3   = (const float*)d_in[6];
    const float* fc1w = (const float*)d_in[7];
    const float* fc1b = (const float*)d_in[8];
    const float* fc2w = (const float*)d_in[9];
    const float* fc2b = (const float*)d_in[10];

    float* out = (float*)d_out;
    float* ws = (float*)d_ws;

    const size_t N1 = (size_t)B_SZ * 16 * 16 * 128;
    const size_t N2 = (size_t)B_SZ * 32 * 8 * 64;
    const size_t N3 = (size_t)B_SZ * 64 * 4 * 32;

    size_t off = 0;
    float* syn1  = ws + off; off += N1;
    float* mem1a = ws + off; off += N1;
    float* mem1b = ws + off; off += N1;
    float* syn2  = ws + off; off += N2;
    float* mem2a = ws + off; off += N2;
    float* mem2b = ws + off; off += N2;
    float* syn3  = ws + off; off += N3;
    float* mem3a = ws + off; off += N3;
    float* mem3b = ws + off; off += N3;
    float* mem4  = ws + off; off += (size_t)B_SZ * 512;
    float* mem5  = ws + off; off += (size_t)B_SZ * 2;
    const size_t zero_elems = off;
    float* spk4 = ws + off; off += (size_t)B_SZ * 512;
    float* wr1  = ws + off; off += (size_t)4 * 16 * 17 * 9;
    float* wr2  = ws + off; off += (size_t)4 * 32 * 48 * 9;
    float* wr3  = ws + off; off += (size_t)4 * 64 * 96 * 9;

    hipMemsetAsync(d_ws, 0, zero_elems * sizeof(float), stream);

    repack_kernel<<<64, 256, 0, stream>>>(w1, wr1, 16, 17);
    repack_kernel<<<64, 256, 0, stream>>>(w2, wr2, 32, 48);
    repack_kernel<<<64, 256, 0, stream>>>(w3, wr3, 64, 96);

    float* m1r = mem1a; float* m1w = mem1b;
    float* m2r = mem2a; float* m2w = mem2b;
    float* m3r = mem3a; float* m3w = mem3b;

    for (int t = 0; t < T_STEPS; ++t) {
        const float* xt = x + (size_t)t * B_SZ * 16 * 128;

        // L1: P=4, R=2, CSPLIT=2, CHUNK=17 (1 round), CITERS=2, UF=1.
        //     grid 64*8*2 = 1024, LDS 35.9KB -> 4 blocks/CU
        conv_lstm<1, 16, 16, 128, 2, 2, 17, false, 4, 4, 1><<<1024, 256, 0, stream>>>(
            xt, m1r, syn1, syn1, m1w, wr1, b1);
        // L2: P=4, R=4, CSPLIT=8, CHUNK=24 (2 rounds), CITERS=1, UF=4.
        //     grid 64*2*8 = 1024, LDS 38.3KB -> 4 blocks/CU
        conv_lstm<16, 32, 8, 64, 4, 8, 24, true, 4, 4, 4><<<1024, 256, 0, stream>>>(
            m1w, m2r, syn2, syn2, m2w, wr2, b2);
        // L3: P=2, R=4, CSPLIT=16, CHUNK=32 (3 rounds), CITERS=1, UF=4.
        //     grid 64*16 = 1024, LDS 27KB -> 4 blocks/CU (round-4 proven + UF)
        conv_lstm<32, 64, 4, 32, 4, 16, 32, true, 4, 2, 4><<<1024, 256, 0, stream>>>(
            m2w, m3r, syn3, syn3, m3w, wr3, b3);

        fc1_pool_kernel<<<1024, 256, 0, stream>>>(m3w, fc1w, fc1b, mem4, spk4);
        fc2_kernel<<<32, 256, 0, stream>>>(
            spk4, fc2w, fc2b, mem5, out + (size_t)t * 2 * B_SZ,
            out + 3200 + (size_t)t * 2 * B_SZ);

        float* tmp;
        tmp = m1r; m1r = m1w; m1w = tmp;
        tmp = m2r; m2r = m2w; m2w = tmp;
        tmp = m3r; m3r = m3w; m3w = tmp;
    }
}

// Round 7
// 3277.588 us; speedup vs baseline: 1.8711x; 1.3566x over previous
//
#include <hip/hip_runtime.h>
#include <math.h>

#define THR  0.05f
#define BETA 0.9181805491303656f
#define B_SZ 64
#define T_STEPS 25

using h8    = __attribute__((ext_vector_type(8))) _Float16;
using f32x4 = __attribute__((ext_vector_type(4))) float;

__device__ __forceinline__ float sigf(float x) { return 1.0f / (1.0f + __expf(-x)); }
__device__ __forceinline__ float tanh_fast(float x) {
    const float xc = fminf(fmaxf(x, -10.0f), 10.0f);
    const float e = __expf(2.0f * xc);
    return (e - 1.0f) / (e + 1.0f);
}

// ---------------------------------------------------------------------------
// Repack conv weights (4*Ch, CIN, 3, 3) OIHW -> [c][ci][tap][gate] (fp32 L1 path)
// ---------------------------------------------------------------------------
__global__ __launch_bounds__(256) void repack_kernel(
    const float* __restrict__ wt, float* __restrict__ wr, int Ch, int CIN)
{
    const int n = 4 * Ch * CIN * 9;
    for (int i = blockIdx.x * 256 + threadIdx.x; i < n; i += gridDim.x * 256) {
        const int g   = i & 3;
        const int tap = (i >> 2) % 9;
        const int ci  = (i / 36) % CIN;
        const int c   = i / (36 * CIN);
        wr[i] = wt[(((size_t)(g * Ch + c)) * CIN + ci) * 9 + tap];
    }
}

// ---------------------------------------------------------------------------
// Repack conv weights into MFMA B-fragment order, fp16 hi/lo split planes.
// flat[((tap*KS + ks)*NG + ng)*512 + l*8 + j] = W[o = ng*16 + (l&15)]
//   [ci = ks*32 + (l>>4)*8 + j][tap], 0 when ci >= CIN (K zero-padding).
// ---------------------------------------------------------------------------
__global__ __launch_bounds__(256) void repack_mfma_kernel(
    const float* __restrict__ wt, _Float16* __restrict__ whi, _Float16* __restrict__ wlo,
    int Ch, int CIN, int KS)
{
    const int NG = (4 * Ch) / 16;
    const int n = 9 * KS * NG * 512;
    for (int i = blockIdx.x * 256 + threadIdx.x; i < n; i += gridDim.x * 256) {
        const int j   = i & 7;
        const int l   = (i >> 3) & 63;
        const int ng  = (i >> 9) % NG;
        const int ks  = (i / (512 * NG)) % KS;
        const int tap = i / (512 * NG * KS);
        const int o   = ng * 16 + (l & 15);
        const int ci  = ks * 32 + ((l >> 4) << 3) + j;
        const float w = (ci < CIN) ? wt[((size_t)o * CIN + ci) * 9 + tap] : 0.0f;
        const _Float16 hi = (_Float16)w;
        whi[i] = hi;
        wlo[i] = (_Float16)(w - (float)hi);
    }
}

// ---------------------------------------------------------------------------
// MFMA ConvLSTM (fp16-split implicit GEMM, NHWC LDS tile, fused LSTM epilogue).
// Block = one image x 16-channel group x 4 gates x H_T output rows.
// A-frag: ds_read_b128 from NHWC tile (tap = base-offset shift, no im2col).
// B-frag: coalesced dwordx4 from pre-fragmented weights. 3 MFMAs per k-step
// (Ah*Wh + Ah*Wl + Al*Wh) give fp32-class accuracy at MFMA rate.
// ---------------------------------------------------------------------------
template<int CSPK, int Ch, int H, int W, int H_T, int KS>
__global__ __launch_bounds__(256) void convlstm_mfma(
    const float* __restrict__ poolin,  // (B, CSPK, 2H, 2W) pre-pool membrane
    const float* __restrict__ memin,   // (B, Ch, H, W)
    const float* __restrict__ synin,
    float* __restrict__ synout,
    float* __restrict__ memout,
    const _Float16* __restrict__ whi,
    const _Float16* __restrict__ wlo,
    const float* __restrict__ bias)    // (4*Ch)
{
    constexpr int CIN   = CSPK + Ch;
    constexpr int CIN_S = CIN + 8;            // +8 fp16: bank-conflict pad, 16B-mult
    constexpr int W2    = W + 2;
    constexpr int ROWS  = (H_T + 2) * W2;
    constexpr int NELEM = ROWS * CIN_S + 16;  // slack covers K-pad overread
    constexpr int NCG   = Ch / 16;
    constexpr int MSPLIT = H / H_T;
    constexpr int M_T   = H_T * W;
    constexpr int WM    = M_T / 4;            // px per wave
    constexpr int MF    = WM / 16;            // M-frags per wave
    constexpr int NG    = (4 * Ch) / 16;
    static_assert(WM % 16 == 0 && W % 16 == 0, "");

    __shared__ _Float16 tileH[NELEM];
    __shared__ _Float16 tileL[NELEM];

    const int tid = threadIdx.x;
    const int bid = blockIdx.x;
    const int cg = bid % NCG;
    const int ms = (bid / NCG) % MSPLIT;
    const int b  = bid / (NCG * MSPLIT);
    const int y0 = ms * H_T;
    const int c0 = cg * 16;

    // zero both planes (covers pad rows/cols, ci-pad, slack)
    {
        uint32_t* p0 = (uint32_t*)tileH;
        uint32_t* p1 = (uint32_t*)tileL;
        for (int i = tid; i < NELEM / 2; i += 256) { p0[i] = 0u; p1[i] = 0u; }
    }
    __syncthreads();

    // fill real elements, x fastest for coalescing; pooled spike for ci<CSPK
    for (int i = tid; i < CIN * (H_T + 2) * W; i += 256) {
        const int x  = i % W;
        const int ry = (i / W) % (H_T + 2);
        const int ci = i / (W * (H_T + 2));
        const int y  = y0 + ry - 1;
        if (y < 0 || y >= H) continue;
        float v;
        if (ci < CSPK) {
            const float* mp = poolin + (((size_t)b * CSPK + ci) * (2 * H) + 2 * y) * (2 * W) + 2 * x;
            const float2 q0 = *(const float2*)mp;
            const float2 q1 = *(const float2*)(mp + 2 * W);
            v = ((fmaxf(fmaxf(q0.x, q0.y), fmaxf(q1.x, q1.y)) - THR) > 0.0f) ? 1.0f : 0.0f;
        } else {
            v = memin[(((size_t)b * Ch + (ci - CSPK)) * H + y) * W + x];
        }
        const _Float16 hi = (_Float16)v;
        const int off = (ry * W2 + x + 1) * CIN_S + ci;
        tileH[off] = hi;
        tileL[off] = (_Float16)(v - (float)hi);
    }
    __syncthreads();

    const int lane = tid & 63;
    const int wid  = tid >> 6;
    const int l15  = lane & 15;
    const int lk8  = (lane >> 4) << 3;   // k offset 0/8/16/24

    // accumulators init with bias: acc[m][gate], C-frag col = l15 -> channel
    f32x4 acc[MF][4];
    #pragma unroll
    for (int g = 0; g < 4; ++g) {
        const float bb = bias[g * Ch + c0 + l15];
        #pragma unroll
        for (int m = 0; m < MF; ++m) acc[m][g] = f32x4{bb, bb, bb, bb};
    }

    #pragma unroll 3
    for (int tap = 0; tap < 9; ++tap) {
        const int dy = tap / 3, dx = tap % 3;
        #pragma unroll
        for (int ks = 0; ks < KS; ++ks) {
            h8 bh[4], bl[4];
            #pragma unroll
            for (int g = 0; g < 4; ++g) {
                const size_t base = ((((size_t)tap * KS + ks) * NG + g * NCG + cg) * 64 + lane) * 8;
                bh[g] = *(const h8*)(whi + base);
                bl[g] = *(const h8*)(wlo + base);
            }
            #pragma unroll
            for (int m = 0; m < MF; ++m) {
                const int pxf = wid * WM + m * 16;
                const int yl = pxf / W;
                const int xf = pxf % W;
                const int off = ((yl + dy) * W2 + xf + l15 + dx) * CIN_S + ks * 32 + lk8;
                const h8 ah = *(const h8*)(tileH + off);
                const h8 al = *(const h8*)(tileL + off);
                #pragma unroll
                for (int g = 0; g < 4; ++g) {
                    acc[m][g] = __builtin_amdgcn_mfma_f32_16x16x32_f16(ah, bh[g], acc[m][g], 0, 0, 0);
                    acc[m][g] = __builtin_amdgcn_mfma_f32_16x16x32_f16(ah, bl[g], acc[m][g], 0, 0, 0);
                    acc[m][g] = __builtin_amdgcn_mfma_f32_16x16x32_f16(al, bh[g], acc[m][g], 0, 0, 0);
                }
            }
        }
    }

    // fused LSTM epilogue: C-frag row = (lane>>4)*4 + j -> pixel, col -> channel
    #pragma unroll
    for (int m = 0; m < MF; ++m) {
        const int pxf = wid * WM + m * 16;
        const int yl = pxf / W;
        const int xf = pxf % W;
        const int c = c0 + l15;
        #pragma unroll
        for (int j = 0; j < 4; ++j) {
            const int x = xf + ((lane >> 4) << 2) + j;
            const size_t gaddr = (((size_t)b * Ch + c) * H + (y0 + yl)) * W + x;
            const float gi = acc[m][0][j], gf = acc[m][1][j];
            const float gg = acc[m][2][j], go = acc[m][3][j];
            const float syn = sigf(gf) * synin[gaddr] + sigf(gi) * tanh_fast(gg);
            synout[gaddr] = syn;
            memout[gaddr] = sigf(go) * tanh_fast(syn);
        }
    }
}

// ---------------------------------------------------------------------------
// fp32 ConvLSTM (proven path, used for L1): wave-per-channel, s_load weights.
// ---------------------------------------------------------------------------
template<int Cin, int Ch, int H, int W, int R, int CSPLIT, int CHUNK,
         bool POOL_IN, int MINW, int P, int UF>
__global__ __launch_bounds__(256, MINW) void conv_lstm(
    const float* __restrict__ xin,
    const float* __restrict__ memin,
    const float* __restrict__ synin,
    float* __restrict__ synout,
    float* __restrict__ memout,
    const float* __restrict__ wr,     // repacked [c][ci][tap][gate]
    const float* __restrict__ bias)
{
    constexpr int CIN = Cin + Ch;
    constexpr int R2 = R + 2;
    constexpr int SW = W + 4;
    constexpr int ROWLANES = W / P;
    constexpr int SPAIRS = W / 2;
    constexpr int NROUNDS = CIN / CHUNK;
    constexpr int CITERS = Ch / (CSPLIT * 4);
    static_assert(R * ROWLANES == 64, "");
    static_assert(CIN % CHUNK == 0, "");
    static_assert(CHUNK % UF == 0, "");

    __shared__ float tile[CHUNK * R2 * SW];

    const int tid = threadIdx.x;
    const int bid = blockIdx.x;
    const int cs = bid % CSPLIT;
    const int rs = (bid / CSPLIT) % (H / R);
    const int b  = bid / (CSPLIT * (H / R));
    const int r0 = rs * R;
    const int c0 = cs * (Ch / CSPLIT);

    const int lane = tid & 63;
    const int wid  = tid >> 6;
    const int ly   = lane / ROWLANES;
    const int lx   = P * (lane % ROWLANES);
    const int gy_out = r0 + ly;

    int cu[CITERS];
    #pragma unroll
    for (int k = 0; k < CITERS; ++k)
        cu[k] = __builtin_amdgcn_readfirstlane(c0 + k * 4 + wid);

    float acc[CITERS][4 * P];
    #pragma unroll
    for (int k = 0; k < CITERS; ++k) {
        const float bi = bias[cu[k]];
        const float bf = bias[cu[k] + Ch];
        const float bg = bias[cu[k] + 2 * Ch];
        const float bo = bias[cu[k] + 3 * Ch];
        #pragma unroll
        for (int p = 0; p < P; ++p) {
            acc[k][0 * P + p] = bi;
            acc[k][1 * P + p] = bf;
            acc[k][2 * P + p] = bg;
            acc[k][3 * P + p] = bo;
        }
    }

    for (int rd = 0; rd < NROUNDS; ++rd) {
        const int k0 = rd * CHUNK;
        if (rd) __syncthreads();

        for (int i = tid; i < CHUNK * R2 * 4; i += 256) {
            const int col = i & 3;
            const int row = i >> 2;
            tile[row * SW + (col == 0 ? 0 : W + col)] = 0.0f;
        }
        for (int i = tid; i < CHUNK * R2 * SPAIRS; i += 256) {
            const int px  = i % SPAIRS;
            const int ry  = (i / SPAIRS) % R2;
            const int cil = i / (SPAIRS * R2);
            const int ci  = k0 + cil;
            const int gy  = r0 + ry - 1;
            float vx = 0.0f, vy = 0.0f;
            if (gy >= 0 && gy < H) {
                if (POOL_IN && ci < Cin) {
                    const float* mp = xin + (((size_t)b * Cin + ci) * (2 * H) + 2 * gy) * (2 * W) + 4 * px;
                    const float4 q0 = *(const float4*)mp;
                    const float4 q1 = *(const float4*)(mp + 2 * W);
                    vx = ((fmaxf(fmaxf(q0.x, q0.y), fmaxf(q1.x, q1.y)) - THR) > 0.0f) ? 1.0f : 0.0f;
                    vy = ((fmaxf(fmaxf(q0.z, q0.w), fmaxf(q1.z, q1.w)) - THR) > 0.0f) ? 1.0f : 0.0f;
                } else if (ci < Cin) {
                    const float2 q = *(const float2*)(xin + (((size_t)b * Cin + ci) * H + gy) * W + 2 * px);
                    vx = q.x; vy = q.y;
                } else {
                    const float2 q = *(const float2*)(memin + (((size_t)b * Ch + (ci - Cin)) * H + gy) * W + 2 * px);
                    vx = q.x; vy = q.y;
                }
            }
            const int t0 = (cil * R2 + ry) * SW + 1 + 2 * px;
            tile[t0]     = vx;
            tile[t0 + 1] = vy;
        }
        __syncthreads();

        #pragma unroll 1
        for (int cil0 = 0; cil0 < CHUNK; cil0 += UF) {
            #pragma unroll
            for (int u = 0; u < UF; ++u) {
                const int cil = cil0 + u;
                float s[3][P + 2];
                #pragma unroll
                for (int dy = 0; dy < 3; ++dy) {
                    const float* rp = &tile[(cil * R2 + ly + dy) * SW + lx];
                    if constexpr (P == 4) {
                        const float4 a  = *(const float4*)rp;
                        const float2 e  = *(const float2*)(rp + 4);
                        s[dy][0] = a.x; s[dy][1] = a.y; s[dy][2] = a.z; s[dy][3] = a.w;
                        s[dy][4] = e.x; s[dy][5] = e.y;
                    } else {
                        const float2 a  = *(const float2*)rp;
                        const float2 e  = *(const float2*)(rp + 2);
                        s[dy][0] = a.x; s[dy][1] = a.y; s[dy][2] = e.x; s[dy][3] = e.y;
                    }
                }
                #pragma unroll
                for (int k = 0; k < CITERS; ++k) {
                    const float* wp = wr + ((size_t)cu[k] * CIN + (k0 + cil)) * 36;
                    #pragma unroll
                    for (int tap = 0; tap < 9; ++tap) {
                        const int dy = tap / 3, dx = tap % 3;
                        const float wi  = wp[tap * 4 + 0];
                        const float wf  = wp[tap * 4 + 1];
                        const float wg_ = wp[tap * 4 + 2];
                        const float wo  = wp[tap * 4 + 3];
                        #pragma unroll
                        for (int p = 0; p < P; ++p) {
                            const float v = s[dy][p + dx];
                            acc[k][0 * P + p] = fmaf(v, wi,  acc[k][0 * P + p]);
                            acc[k][1 * P + p] = fmaf(v, wf,  acc[k][1 * P + p]);
                            acc[k][2 * P + p] = fmaf(v, wg_, acc[k][2 * P + p]);
                            acc[k][3 * P + p] = fmaf(v, wo,  acc[k][3 * P + p]);
                        }
                    }
                }
            }
        }
    }

    #pragma unroll
    for (int k = 0; k < CITERS; ++k) {
        const int c = c0 + k * 4 + wid;
        const size_t base = (((size_t)b * Ch + c) * H + gy_out) * W + lx;
        float sv[P], so[P], mo[P];
        if constexpr (P == 4) {
            const float4 q = *(const float4*)(synin + base);
            sv[0] = q.x; sv[1] = q.y; sv[2] = q.z; sv[3] = q.w;
        } else {
            const float2 q = *(const float2*)(synin + base);
            sv[0] = q.x; sv[1] = q.y;
        }
        #pragma unroll
        for (int p = 0; p < P; ++p) {
            const float syn = sigf(acc[k][1 * P + p]) * sv[p]
                            + sigf(acc[k][0 * P + p]) * tanh_fast(acc[k][2 * P + p]);
            so[p] = syn;
            mo[p] = sigf(acc[k][3 * P + p]) * tanh_fast(syn);
        }
        if constexpr (P == 4) {
            *(float4*)(synout + base) = make_float4(so[0], so[1], so[2], so[3]);
            *(float4*)(memout + base) = make_float4(mo[0], mo[1], mo[2], mo[3]);
        } else {
            *(float2*)(synout + base) = make_float2(so[0], so[1]);
            *(float2*)(memout + base) = make_float2(mo[0], mo[1]);
        }
    }
}

// ---------------------------------------------------------------------------
// Fused maxpool(m3) -> spk3 -> cur4 = spk3 @ fc1_w.T + b -> Leaky(mem4).
// ---------------------------------------------------------------------------
__global__ __launch_bounds__(256) void fc1_pool_kernel(
    const float* __restrict__ m3,    // (B, 64, 4, 32)
    const float* __restrict__ wt,    // (512, 2048)
    const float* __restrict__ bias,
    float* __restrict__ mem4,
    float* __restrict__ spk4)
{
    const int wid = (blockIdx.x * 256 + threadIdx.x) >> 6;
    const int lane = threadIdx.x & 63;
    const int og = wid & 63;
    const int b = wid >> 6;
    const int o0 = og * 8;

    float acc[8] = {0, 0, 0, 0, 0, 0, 0, 0};
    for (int it = 0; it < 8; ++it) {
        const int k = (it * 64 + lane) * 4;
        const int c = k >> 5;
        const int rem = k & 31;
        const int ph = rem >> 4;
        const int pw = rem & 15;
        const float* mp = m3 + (((size_t)b * 64 + c) * 4 + 2 * ph) * 32 + 2 * pw;
        const float4 r0 = *(const float4*)mp;
        const float4 r1 = *(const float4*)(mp + 4);
        const float4 q0 = *(const float4*)(mp + 32);
        const float4 q1 = *(const float4*)(mp + 36);
        float4 sv;
        sv.x = ((fmaxf(fmaxf(r0.x, r0.y), fmaxf(q0.x, q0.y)) - THR) > 0.0f) ? 1.0f : 0.0f;
        sv.y = ((fmaxf(fmaxf(r0.z, r0.w), fmaxf(q0.z, q0.w)) - THR) > 0.0f) ? 1.0f : 0.0f;
        sv.z = ((fmaxf(fmaxf(r1.x, r1.y), fmaxf(q1.x, q1.y)) - THR) > 0.0f) ? 1.0f : 0.0f;
        sv.w = ((fmaxf(fmaxf(r1.z, r1.w), fmaxf(q1.z, q1.w)) - THR) > 0.0f) ? 1.0f : 0.0f;
        #pragma unroll
        for (int j = 0; j < 8; ++j) {
            const float4 wv = *(const float4*)(wt + (size_t)(o0 + j) * 2048 + k);
            acc[j] = fmaf(sv.x, wv.x, acc[j]);
            acc[j] = fmaf(sv.y, wv.y, acc[j]);
            acc[j] = fmaf(sv.z, wv.z, acc[j]);
            acc[j] = fmaf(sv.w, wv.w, acc[j]);
        }
    }
    float mine = 0.0f;
    #pragma unroll
    for (int j = 0; j < 8; ++j) {
        float a = acc[j];
        #pragma unroll
        for (int off = 32; off; off >>= 1) a += __shfl_xor(a, off, 64);
        if (lane == j) mine = a;
    }
    if (lane < 8) {
        const int o = o0 + lane;
        const float cur = mine + bias[o];
        const int i4 = b * 512 + o;
        float m = mem4[i4];
        const float reset = (m > THR) ? 1.0f : 0.0f;
        m = BETA * m + cur - reset * THR;
        spk4[i4] = ((m - THR) > 0.0f) ? 1.0f : 0.0f;
        mem4[i4] = m;
    }
}

// ---------------------------------------------------------------------------
// cur5 = spk4 @ fc2_w.T + fc2_b; Leaky(mem5); writes spk_rec[t], mem_rec[t].
// ---------------------------------------------------------------------------
__global__ __launch_bounds__(256) void fc2_kernel(
    const float* __restrict__ spk4,
    const float* __restrict__ wt,
    const float* __restrict__ bias,
    float* __restrict__ mem5,
    float* __restrict__ out_spk,
    float* __restrict__ out_mem)
{
    const int wid = (blockIdx.x * 256 + threadIdx.x) >> 6;
    const int lane = threadIdx.x & 63;
    if (wid >= 2 * B_SZ) return;
    const int o = wid & 1;
    const int b = wid >> 1;
    const float* wr = wt + (size_t)o * 512;
    const float* sr = spk4 + (size_t)b * 512;
    float acc = 0.0f;
    #pragma unroll
    for (int i = 0; i < 8; ++i)
        acc = fmaf(sr[lane + i * 64], wr[lane + i * 64], acc);
    #pragma unroll
    for (int off = 32; off; off >>= 1) acc += __shfl_down(acc, off, 64);
    if (lane == 0) {
        const float cur = acc + bias[o];
        const int i5 = b * 2 + o;
        float m = mem5[i5];
        const float reset = (m > THR) ? 1.0f : 0.0f;
        m = BETA * m + cur - reset * THR;
        out_spk[i5] = ((m - THR) > 0.0f) ? 1.0f : 0.0f;
        out_mem[i5] = m;
        mem5[i5] = m;
    }
}

extern "C" void kernel_launch(void* const* d_in, const int* in_sizes, int n_in,
                              void* d_out, int out_size, void* d_ws, size_t ws_size,
                              hipStream_t stream) {
    (void)in_sizes; (void)n_in; (void)out_size; (void)ws_size;

    const float* x    = (const float*)d_in[0];
    const float* w1   = (const float*)d_in[1];
    const float* b1   = (const float*)d_in[2];
    const float* w2   = (const float*)d_in[3];
    const float* b2   = (const float*)d_in[4];
    const float* w3   = (const float*)d_in[5];
    const float* b3   = (const float*)d_in[6];
    const float* fc1w = (const float*)d_in[7];
    const float* fc1b = (const float*)d_in[8];
    const float* fc2w = (const float*)d_in[9];
    const float* fc2b = (const float*)d_in[10];

    float* out = (float*)d_out;
    float* ws = (float*)d_ws;

    const size_t N1 = (size_t)B_SZ * 16 * 16 * 128;
    const size_t N2 = (size_t)B_SZ * 32 * 8 * 64;
    const size_t N3 = (size_t)B_SZ * 64 * 4 * 32;

    size_t off = 0;
    float* syn1  = ws + off; off += N1;
    float* mem1a = ws + off; off += N1;
    float* mem1b = ws + off; off += N1;
    float* syn2  = ws + off; off += N2;
    float* mem2a = ws + off; off += N2;
    float* mem2b = ws + off; off += N2;
    float* syn3  = ws + off; off += N3;
    float* mem3a = ws + off; off += N3;
    float* mem3b = ws + off; off += N3;
    float* mem4  = ws + off; off += (size_t)B_SZ * 512;
    float* mem5  = ws + off; off += (size_t)B_SZ * 2;
    const size_t zero_elems = off;
    float* spk4 = ws + off; off += (size_t)B_SZ * 512;
    float* wr1  = ws + off; off += (size_t)4 * 16 * 17 * 9;
    // fp16 fragment-ordered weight planes (element counts are fp16; /2 floats)
    _Float16* whi2 = (_Float16*)(ws + off); off += 36864;   // 9*2*8*512 fp16
    _Float16* wlo2 = (_Float16*)(ws + off); off += 36864;
    _Float16* whi3 = (_Float16*)(ws + off); off += 110592;  // 9*3*16*512 fp16
    _Float16* wlo3 = (_Float16*)(ws + off); off += 110592;

    hipMemsetAsync(d_ws, 0, zero_elems * sizeof(float), stream);

    repack_kernel<<<64, 256, 0, stream>>>(w1, wr1, 16, 17);
    repack_mfma_kernel<<<288, 256, 0, stream>>>(w2, whi2, wlo2, 32, 48, 2);
    repack_mfma_kernel<<<864, 256, 0, stream>>>(w3, whi3, wlo3, 64, 96, 3);

    float* m1r = mem1a; float* m1w = mem1b;
    float* m2r = mem2a; float* m2w = mem2b;
    float* m3r = mem3a; float* m3w = mem3b;

    for (int t = 0; t < T_STEPS; ++t) {
        const float* xt = x + (size_t)t * B_SZ * 16 * 128;

        // L1 (fp32 path): P=4, R=2, CSPLIT=2, CHUNK=17, grid 1024
        conv_lstm<1, 16, 16, 128, 2, 2, 17, false, 4, 4, 1><<<1024, 256, 0, stream>>>(
            xt, m1r, syn1, syn1, m1w, wr1, b1);

        // L2 (MFMA): CSPK=16, Ch=32, H=8, W=64, H_T=2, KS=2
        //   grid = B * (Ch/16) * (H/H_T) = 64*2*4 = 512, LDS ~58KB
        convlstm_mfma<16, 32, 8, 64, 2, 2><<<512, 256, 0, stream>>>(
            m1w, m2r, syn2, syn2, m2w, whi2, wlo2, b2);

        // L3 (MFMA): CSPK=32, Ch=64, H=4, W=32, H_T=2, KS=3
        //   grid = 64*4*2 = 512, LDS ~55KB
        convlstm_mfma<32, 64, 4, 32, 2, 3><<<512, 256, 0, stream>>>(
            m2w, m3r, syn3, syn3, m3w, whi3, wlo3, b3);

        fc1_pool_kernel<<<1024, 256, 0, stream>>>(m3w, fc1w, fc1b, mem4, spk4);
        fc2_kernel<<<32, 256, 0, stream>>>(
            spk4, fc2w, fc2b, mem5, out + (size_t)t * 2 * B_SZ,
            out + 3200 + (size_t)t * 2 * B_SZ);

        float* tmp;
        tmp = m1r; m1r = m1w; m1w = tmp;
        tmp = m2r; m2r = m2w; m2w = tmp;
        tmp = m3r; m3r = m3w; m3w = tmp;
    }
}